// Round 9
// baseline (530.749 us; speedup 1.0000x reference)
//
#include <hip/hip_runtime.h>

#define DIM   1024
#define HID   2048
#define NE    8
#define T_TOK 4096

typedef __attribute__((ext_vector_type(8))) short short8;
typedef __attribute__((ext_vector_type(4))) float f32x4;

__device__ __forceinline__ ushort f2bf(float f) {
    union { float f; unsigned u; } v; v.f = f;
    unsigned r = v.u + 0x7FFFu + ((v.u >> 16) & 1u);   // RNE
    return (ushort)(r >> 16);
}

__device__ __forceinline__ float gelu_exact(float x) {
    return 0.5f * x * (1.0f + erff(x * 0.70710678118654752f));
}

// ---------------- convert x (fp32 -> bf16) ----------------
__global__ void convert_x(const float* __restrict__ in, ushort* __restrict__ out, int n8) {
    int i = blockIdx.x * blockDim.x + threadIdx.x;
    if (i >= n8) return;
    const float4* p = (const float4*)in + (size_t)i * 2;
    float4 a = p[0], b = p[1];
    short8 o;
    o[0] = (short)f2bf(a.x); o[1] = (short)f2bf(a.y);
    o[2] = (short)f2bf(a.z); o[3] = (short)f2bf(a.w);
    o[4] = (short)f2bf(b.x); o[5] = (short)f2bf(b.y);
    o[6] = (short)f2bf(b.z); o[7] = (short)f2bf(b.w);
    *(short8*)(out + (size_t)i * 8) = o;
}

// ------- transpose+convert, 9 tensors in one launch: z<8 experts, z=8 shared -------
__global__ void transpose_conv9(const float* __restrict__ ew, const float* __restrict__ sw,
                                ushort* __restrict__ ewT, ushort* __restrict__ swT,
                                int R, int C) {
    __shared__ float tile[32][65];
    int z = blockIdx.z;
    const float* in = (z < NE) ? ew + (size_t)z * R * C : sw;
    ushort* out     = (z < NE) ? ewT + (size_t)z * R * C : swT;
    int c0 = blockIdx.x * 32, r0 = blockIdx.y * 64;
    int tx = threadIdx.x & 31, ty = threadIdx.x >> 5;   // 256 threads
#pragma unroll
    for (int rr = 0; rr < 64; rr += 8)
        tile[tx][rr + ty] = in[(size_t)(r0 + rr + ty) * C + (c0 + tx)];
    __syncthreads();
    int lane = threadIdx.x & 63, q = threadIdx.x >> 6;
#pragma unroll
    for (int j = 0; j < 8; ++j) {
        int cc = q * 8 + j;
        out[(size_t)(c0 + cc) * R + (r0 + lane)] = f2bf(tile[cc][lane]);
    }
}

// ---------------- router: top-2 of softmax(x @ rw + rb), renormalized ----------------
__global__ void router_kernel(const float* __restrict__ x, const float* __restrict__ rw,
                              const float* __restrict__ rb, int* __restrict__ cnt,
                              int* __restrict__ ids, float* __restrict__ wts) {
    int wave = threadIdx.x >> 6;
    int lane = threadIdx.x & 63;
    int t = blockIdx.x * 4 + wave;
    const float* xr = x + (size_t)t * DIM;
    float acc[NE];
#pragma unroll
    for (int e = 0; e < NE; ++e) acc[e] = 0.f;
    for (int d = lane; d < DIM; d += 64) {
        float xv = xr[d];
#pragma unroll
        for (int e = 0; e < NE; ++e) acc[e] += xv * rw[d * NE + e];
    }
#pragma unroll
    for (int e = 0; e < NE; ++e) {
#pragma unroll
        for (int off = 32; off; off >>= 1) acc[e] += __shfl_xor(acc[e], off);
    }
    if (lane == 0) {
        float l[NE];
#pragma unroll
        for (int e = 0; e < NE; ++e) l[e] = acc[e] + rb[e];
        int i1 = 0;
#pragma unroll
        for (int e = 1; e < NE; ++e) if (l[e] > l[i1]) i1 = e;
        int i2 = (i1 == 0) ? 1 : 0;
#pragma unroll
        for (int e = 0; e < NE; ++e) if (e != i1 && l[e] > l[i2]) i2 = e;
        float p2 = __expf(l[i2] - l[i1]);      // p1 = 1
        float w1 = 1.0f / (1.0f + p2);
        float w2 = p2 / (1.0f + p2);
        int pos1 = atomicAdd(&cnt[i1], 1);
        ids[i1 * T_TOK + pos1] = t; wts[i1 * T_TOK + pos1] = w1;
        int pos2 = atomicAdd(&cnt[i2], 1);
        ids[i2 * T_TOK + pos2] = t; wts[i2 * T_TOK + pos2] = w2;
    }
}

__global__ void offsets_kernel(const int* __restrict__ cnt, int* __restrict__ offs) {
    if (threadIdx.x == 0) {
        int s = 0;
        for (int e = 0; e < NE; ++e) { offs[e] = s; s += cnt[e]; }
    }
}

// ===== 256x256 tile, BK=64, 8 waves (2Mx4N), double-buffered LDS, COUNTED vmcnt =====
// LDS: 2 bufs x (A 256x64 + B 256x64) bf16 = 128 KiB (dynamic) -> 1 block/CU, 2 waves/SIMD.
// Layout [row][64] with element-column XOR swizzle ((row&7)<<3), applied on the
// GLOBAL source column so global_load_lds destinations stay linear.
// Schedule (T4): STAGE(next) at phase top, then s_waitcnt vmcnt(8) — waits ONLY
// for the current tile's 8 loads; next tile's 8 stay in flight across COMPUTE.
__device__ __forceinline__ void mma256(
    const ushort* __restrict__ A, const int* __restrict__ gather, int count,
    const ushort* __restrict__ BT, int K, int tileM, int tileN,
    ushort* lds, f32x4 acc[8][4])
{
    const int tid  = threadIdx.x;
    const int lane = tid & 63, wave = tid >> 6;       // 8 waves
    const int wr = wave >> 2, wc = wave & 3;          // 2M x 4N
    const int g = lane >> 4, fr = lane & 15;
    const int sub = lane >> 3;                        // row within 8-row chunk
    const int kcs = ((lane & 7) ^ sub) << 3;          // pre-swizzled global col

    const ushort* asrc[4];
    const ushort* bsrc[4];
#pragma unroll
    for (int i = 0; i < 4; ++i) {
        int row = (wave * 4 + i) * 8 + sub;           // 32 chunks cover 256 rows
        int ar = tileM + row; if (ar > count - 1) ar = count - 1;
        int grow = gather ? gather[ar] : ar;
        asrc[i] = A  + (size_t)grow * K + kcs;
        bsrc[i] = BT + (size_t)(tileN + row) * K + kcs;
    }

    auto STAGE = [&](int buf, int t) {
        ushort* base = lds + buf * 32768;             // A at +0, B at +16384 (elems)
#pragma unroll
        for (int i = 0; i < 4; ++i) {
            int chunk = wave * 4 + i;
            __builtin_amdgcn_global_load_lds(
                (const __attribute__((address_space(1))) void*)(asrc[i] + t * 64),
                (__attribute__((address_space(3))) void*)(base + chunk * 512),
                16, 0, 0);
            __builtin_amdgcn_global_load_lds(
                (const __attribute__((address_space(1))) void*)(bsrc[i] + t * 64),
                (__attribute__((address_space(3))) void*)(base + 16384 + chunk * 512),
                16, 0, 0);
        }
    };

    auto COMPUTE = [&](int buf) {
        const ushort* A_s = lds + buf * 32768;
        const ushort* B_s = A_s + 16384;
#pragma unroll
        for (int kk = 0; kk < 2; ++kk) {
            int koff = kk * 32 + g * 8;
            short8 a[8], b[4];
#pragma unroll
            for (int m = 0; m < 8; ++m) {
                int row = wr * 128 + m * 16 + fr;
                a[m] = *(const short8*)&A_s[row * 64 + (koff ^ ((row & 7) << 3))];
            }
#pragma unroll
            for (int n = 0; n < 4; ++n) {
                int col = wc * 64 + n * 16 + fr;
                b[n] = *(const short8*)&B_s[col * 64 + (koff ^ ((col & 7) << 3))];
            }
#pragma unroll
            for (int m = 0; m < 8; ++m)
#pragma unroll
                for (int n = 0; n < 4; ++n)
                    acc[m][n] = __builtin_amdgcn_mfma_f32_16x16x32_bf16(
                        a[m], b[n], acc[m][n], 0, 0, 0);
        }
    };

    const int NT = K >> 6;
    STAGE(0, 0);                                      // 8 loads out
    for (int t = 0; t < NT; ++t) {
        int cur = t & 1;
        if (t + 1 < NT) {
            STAGE(cur ^ 1, t + 1);                    // 16 out
            asm volatile("s_waitcnt vmcnt(8)" ::: "memory");   // tile t landed
        } else {
            asm volatile("s_waitcnt vmcnt(0)" ::: "memory");
        }
        __builtin_amdgcn_s_barrier();
        asm volatile("" ::: "memory");
        COMPUTE(cur);
        asm volatile("" ::: "memory");
        __builtin_amdgcn_s_barrier();                 // buf[cur] free for overwrite
    }
}

// ---------------- GEMM1: h = gelu(X @ W1 + b1), packed per expert ----------------
__global__ __launch_bounds__(512, 2)
void gemm1_kernel(const ushort* __restrict__ xb,
                  const ushort* __restrict__ ew1T, const ushort* __restrict__ sw1T,
                  const float* __restrict__ eb1, const float* __restrict__ sb1,
                  const int* __restrict__ ids, const int* __restrict__ cnt,
                  const int* __restrict__ offs, ushort* __restrict__ h)
{
    extern __shared__ ushort lds[];
    int e = blockIdx.z;
    int count, hbase;
    const ushort* BT; const float* bias; const int* gather;
    if (e < NE) {
        count  = cnt[e];
        BT     = ew1T + (size_t)e * HID * DIM;
        bias   = eb1 + e * HID;
        gather = ids + e * T_TOK;
        hbase  = T_TOK + offs[e];
    } else {
        count = T_TOK; BT = sw1T; bias = sb1; gather = nullptr; hbase = 0;
    }
    int tileM = blockIdx.y * 256, tileN = blockIdx.x * 256;
    if (tileM >= count) return;

    f32x4 acc[8][4];
#pragma unroll
    for (int m = 0; m < 8; ++m)
#pragma unroll
        for (int n = 0; n < 4; ++n) acc[m][n] = (f32x4){0.f, 0.f, 0.f, 0.f};

    mma256(xb, gather, count, BT, DIM, tileM, tileN, lds, acc);

    const int lane = threadIdx.x & 63, wave = threadIdx.x >> 6;
    const int wr = wave >> 2, wc = wave & 3, g = lane >> 4, fr = lane & 15;
#pragma unroll
    for (int n = 0; n < 4; ++n) {
        int col = tileN + wc * 64 + n * 16 + fr;
        float bc = bias[col];
#pragma unroll
        for (int m = 0; m < 8; ++m) {
#pragma unroll
            for (int i = 0; i < 4; ++i) {
                int row = tileM + wr * 128 + m * 16 + g * 4 + i;
                if (row < count)
                    h[(size_t)(hbase + row) * HID + col] =
                        f2bf(gelu_exact(acc[m][n][i] + bc));
            }
        }
    }
}

// ------- GEMM2 (single launch, all-atomic into pre-zeroed out): z<8 experts, z=8 shared -------
__global__ __launch_bounds__(512, 2)
void gemm2_kernel(const ushort* __restrict__ h,
                  const ushort* __restrict__ ew2T, const ushort* __restrict__ sw2T,
                  const float* __restrict__ eb2, const float* __restrict__ sb2,
                  const int* __restrict__ ids, const float* __restrict__ wts,
                  const int* __restrict__ cnt, const int* __restrict__ offs,
                  float* __restrict__ out)
{
    extern __shared__ ushort lds[];
    int e = blockIdx.z;
    int count;
    const ushort* BT; const float* bias; const int* toks; const float* tw;
    const ushort* Arows;
    if (e < NE) {
        count = cnt[e];
        BT    = ew2T + (size_t)e * DIM * HID;
        bias  = eb2 + e * DIM;
        toks  = ids + e * T_TOK;
        tw    = wts + e * T_TOK;
        Arows = h + (size_t)(T_TOK + offs[e]) * HID;
    } else {
        count = T_TOK; BT = sw2T; bias = sb2; toks = nullptr; tw = nullptr;
        Arows = h;
    }
    int tileM = blockIdx.y * 256, tileN = blockIdx.x * 256;
    if (tileM >= count) return;

    f32x4 acc[8][4];
#pragma unroll
    for (int m = 0; m < 8; ++m)
#pragma unroll
        for (int n = 0; n < 4; ++n) acc[m][n] = (f32x4){0.f, 0.f, 0.f, 0.f};

    mma256(Arows, nullptr, count, BT, HID, tileM, tileN, lds, acc);

    const int lane = threadIdx.x & 63, wave = threadIdx.x >> 6;
    const int wr = wave >> 2, wc = wave & 3, g = lane >> 4, fr = lane & 15;
#pragma unroll
    for (int n = 0; n < 4; ++n) {
        int col = tileN + wc * 64 + n * 16 + fr;
        float bc = bias[col];
#pragma unroll
        for (int m = 0; m < 8; ++m) {
#pragma unroll
            for (int i = 0; i < 4; ++i) {
                int row = tileM + wr * 128 + m * 16 + g * 4 + i;
                if (row < count) {
                    int token = toks ? toks[row] : row;
                    float w   = tw ? tw[row] : 1.0f;
                    atomicAdd(out + (size_t)token * DIM + col, w * (acc[m][n][i] + bc));
                }
            }
        }
    }
}

extern "C" void kernel_launch(void* const* d_in, const int* in_sizes, int n_in,
                              void* d_out, int out_size, void* d_ws, size_t ws_size,
                              hipStream_t stream)
{
    const float* x   = (const float*)d_in[0];
    const float* rw  = (const float*)d_in[1];
    const float* rb  = (const float*)d_in[2];
    const float* sw1 = (const float*)d_in[3];
    const float* sb1 = (const float*)d_in[4];
    const float* sw2 = (const float*)d_in[5];
    const float* sb2 = (const float*)d_in[6];
    const float* ew1 = (const float*)d_in[7];
    const float* eb1 = (const float*)d_in[8];
    const float* ew2 = (const float*)d_in[9];
    const float* eb2 = (const float*)d_in[10];
    float* out = (float*)d_out;

    char* p = (char*)d_ws;
    ushort* xb   = (ushort*)p;  p += (size_t)T_TOK * DIM * 2;
    ushort* sw1T = (ushort*)p;  p += (size_t)HID * DIM * 2;
    ushort* sw2T = (ushort*)p;  p += (size_t)DIM * HID * 2;
    ushort* ew1T = (ushort*)p;  p += (size_t)NE * HID * DIM * 2;
    ushort* ew2T = (ushort*)p;  p += (size_t)NE * DIM * HID * 2;
    ushort* hbuf = (ushort*)p;  p += (size_t)(3 * T_TOK) * HID * 2;
    int*    ids  = (int*)p;     p += (size_t)NE * T_TOK * 4;
    float*  wts  = (float*)p;   p += (size_t)NE * T_TOK * 4;
    int*    cnt  = (int*)p;     p += 256;
    int*    offs = (int*)p;     p += 256;

    hipFuncSetAttribute((const void*)gemm1_kernel,
                        hipFuncAttributeMaxDynamicSharedMemorySize, 131072);
    hipFuncSetAttribute((const void*)gemm2_kernel,
                        hipFuncAttributeMaxDynamicSharedMemorySize, 131072);

    hipMemsetAsync(cnt, 0, 256, stream);
    hipMemsetAsync(out, 0, (size_t)out_size * 4, stream);

    convert_x<<<dim3((T_TOK * DIM / 8 + 255) / 256), 256, 0, stream>>>(x, xb, T_TOK * DIM / 8);
    transpose_conv9<<<dim3(HID / 32, DIM / 64, NE + 1), 256, 0, stream>>>(
        ew1, sw1, ew1T, sw1T, DIM, HID);
    transpose_conv9<<<dim3(DIM / 32, HID / 64, NE + 1), 256, 0, stream>>>(
        ew2, sw2, ew2T, sw2T, HID, DIM);
    router_kernel<<<dim3(T_TOK / 4), 256, 0, stream>>>(x, rw, rb, cnt, ids, wts);
    offsets_kernel<<<dim3(1), 64, 0, stream>>>(cnt, offs);
    gemm1_kernel<<<dim3(HID / 256, T_TOK / 256, NE + 1), 512, 131072, stream>>>(
        xb, ew1T, sw1T, eb1, sb1, ids, cnt, offs, hbuf);
    gemm2_kernel<<<dim3(DIM / 256, T_TOK / 256, NE + 1), 512, 131072, stream>>>(
        hbuf, ew2T, sw2T, eb2, sb2, ids, wts, cnt, offs, out);
}

// Round 10
// 416.541 us; speedup vs baseline: 1.2742x; 1.2742x over previous
//
#include <hip/hip_runtime.h>

#define DIM   1024
#define HID   2048
#define NE    8
#define T_TOK 4096

typedef __attribute__((ext_vector_type(8))) short short8;
typedef __attribute__((ext_vector_type(4))) float f32x4;

__device__ __forceinline__ ushort f2bf(float f) {
    union { float f; unsigned u; } v; v.f = f;
    unsigned r = v.u + 0x7FFFu + ((v.u >> 16) & 1u);   // RNE
    return (ushort)(r >> 16);
}

__device__ __forceinline__ float gelu_exact(float x) {
    return 0.5f * x * (1.0f + erff(x * 0.70710678118654752f));
}

// ---------------- convert x (fp32 -> bf16) ----------------
__global__ void convert_x(const float* __restrict__ in, ushort* __restrict__ out, int n8) {
    int i = blockIdx.x * blockDim.x + threadIdx.x;
    if (i >= n8) return;
    const float4* p = (const float4*)in + (size_t)i * 2;
    float4 a = p[0], b = p[1];
    short8 o;
    o[0] = (short)f2bf(a.x); o[1] = (short)f2bf(a.y);
    o[2] = (short)f2bf(a.z); o[3] = (short)f2bf(a.w);
    o[4] = (short)f2bf(b.x); o[5] = (short)f2bf(b.y);
    o[6] = (short)f2bf(b.z); o[7] = (short)f2bf(b.w);
    *(short8*)(out + (size_t)i * 8) = o;
}

// ------- transpose+convert, 9 tensors in one launch: z<8 experts, z=8 shared -------
__global__ void transpose_conv9(const float* __restrict__ ew, const float* __restrict__ sw,
                                ushort* __restrict__ ewT, ushort* __restrict__ swT,
                                int R, int C) {
    __shared__ float tile[32][65];
    int z = blockIdx.z;
    const float* in = (z < NE) ? ew + (size_t)z * R * C : sw;
    ushort* out     = (z < NE) ? ewT + (size_t)z * R * C : swT;
    int c0 = blockIdx.x * 32, r0 = blockIdx.y * 64;
    int tx = threadIdx.x & 31, ty = threadIdx.x >> 5;   // 256 threads
#pragma unroll
    for (int rr = 0; rr < 64; rr += 8)
        tile[tx][rr + ty] = in[(size_t)(r0 + rr + ty) * C + (c0 + tx)];
    __syncthreads();
    int lane = threadIdx.x & 63, q = threadIdx.x >> 6;
#pragma unroll
    for (int j = 0; j < 8; ++j) {
        int cc = q * 8 + j;
        out[(size_t)(c0 + cc) * R + (r0 + lane)] = f2bf(tile[cc][lane]);
    }
}

// ---------------- router: top-2 of softmax(x @ rw + rb), renormalized ----------------
__global__ void router_kernel(const float* __restrict__ x, const float* __restrict__ rw,
                              const float* __restrict__ rb, int* __restrict__ cnt,
                              int* __restrict__ ids, float* __restrict__ wts) {
    int wave = threadIdx.x >> 6;
    int lane = threadIdx.x & 63;
    int t = blockIdx.x * 4 + wave;
    const float* xr = x + (size_t)t * DIM;
    float acc[NE];
#pragma unroll
    for (int e = 0; e < NE; ++e) acc[e] = 0.f;
    for (int d = lane; d < DIM; d += 64) {
        float xv = xr[d];
#pragma unroll
        for (int e = 0; e < NE; ++e) acc[e] += xv * rw[d * NE + e];
    }
#pragma unroll
    for (int e = 0; e < NE; ++e) {
#pragma unroll
        for (int off = 32; off; off >>= 1) acc[e] += __shfl_xor(acc[e], off);
    }
    if (lane == 0) {
        float l[NE];
#pragma unroll
        for (int e = 0; e < NE; ++e) l[e] = acc[e] + rb[e];
        int i1 = 0;
#pragma unroll
        for (int e = 1; e < NE; ++e) if (l[e] > l[i1]) i1 = e;
        int i2 = (i1 == 0) ? 1 : 0;
#pragma unroll
        for (int e = 0; e < NE; ++e) if (e != i1 && l[e] > l[i2]) i2 = e;
        float p2 = __expf(l[i2] - l[i1]);      // p1 = 1
        float w1 = 1.0f / (1.0f + p2);
        float w2 = p2 / (1.0f + p2);
        int pos1 = atomicAdd(&cnt[i1], 1);
        ids[i1 * T_TOK + pos1] = t; wts[i1 * T_TOK + pos1] = w1;
        int pos2 = atomicAdd(&cnt[i2], 1);
        ids[i2 * T_TOK + pos2] = t; wts[i2 * T_TOK + pos2] = w2;
    }
}

// ------- build offsets + persistent-GEMM work queues (single thread; tiny) -------
// item = (z<<16) | (mTile<<8) | nTile.   z: 0..7 experts, 8 = shared.
__global__ void build_queue(const int* __restrict__ cnt, int* __restrict__ offs,
                            int* __restrict__ q1, int* __restrict__ n1,
                            int* __restrict__ q2, int* __restrict__ n2) {
    if (threadIdx.x != 0) return;
    int s = 0;
    for (int e = 0; e < NE; ++e) { offs[e] = s; s += cnt[e]; }
    int k1 = 0, k2 = 0;
    for (int z = 0; z <= NE; ++z) {
        int c = (z < NE) ? cnt[z] : T_TOK;
        int mts = (c + 255) >> 8;
        for (int mt = 0; mt < mts; ++mt) {
            for (int nt = 0; nt < HID / 256; ++nt)
                q1[k1++] = (z << 16) | (mt << 8) | nt;
            for (int nt = 0; nt < DIM / 256; ++nt)
                q2[k2++] = (z << 16) | (mt << 8) | nt;
        }
    }
    *n1 = k1; *n2 = k2;
}

// ===== 256x256 tile, BK=64, 8 waves (2Mx4N), double-buffered LDS, COUNTED vmcnt =====
// LDS: 2 bufs x (A 256x64 + B 256x64) bf16 = 128 KiB -> 1 block/CU, 2 waves/SIMD.
// Layout [row][64] with element-column XOR swizzle ((row&7)<<3), applied on the
// GLOBAL source column so global_load_lds destinations stay linear.
// Schedule (T4): STAGE(next) at phase top, then s_waitcnt vmcnt(8) — waits only
// for the current tile's 8 loads; next tile's 8 stay in flight across COMPUTE.
__device__ __forceinline__ void mma256(
    const ushort* __restrict__ A, const int* __restrict__ gather, int count,
    const ushort* __restrict__ BT, int K, int tileM, int tileN,
    ushort* lds, f32x4 acc[8][4])
{
    const int tid  = threadIdx.x;
    const int lane = tid & 63, wave = tid >> 6;       // 8 waves
    const int wr = wave >> 2, wc = wave & 3;          // 2M x 4N
    const int g = lane >> 4, fr = lane & 15;
    const int swl = (fr & 7) << 3;                    // lane-constant LDS swizzle
    const int sub = lane >> 3;                        // row within 8-row chunk
    const int kcs = ((lane & 7) ^ sub) << 3;          // pre-swizzled global col

    const ushort* asrc[4];
    const ushort* bsrc[4];
#pragma unroll
    for (int i = 0; i < 4; ++i) {
        int row = (wave * 4 + i) * 8 + sub;           // 32 chunks cover 256 rows
        int ar = tileM + row; if (ar > count - 1) ar = count - 1;
        int grow = gather ? gather[ar] : ar;
        asrc[i] = A  + (size_t)grow * K + kcs;
        bsrc[i] = BT + (size_t)(tileN + row) * K + kcs;
    }

    auto STAGE = [&](int buf, int t) {
        ushort* base = lds + buf * 32768;             // A at +0, B at +16384 (elems)
#pragma unroll
        for (int i = 0; i < 4; ++i) {
            int chunk = wave * 4 + i;
            __builtin_amdgcn_global_load_lds(
                (const __attribute__((address_space(1))) void*)(asrc[i] + t * 64),
                (__attribute__((address_space(3))) void*)(base + chunk * 512),
                16, 0, 0);
            __builtin_amdgcn_global_load_lds(
                (const __attribute__((address_space(1))) void*)(bsrc[i] + t * 64),
                (__attribute__((address_space(3))) void*)(base + 16384 + chunk * 512),
                16, 0, 0);
        }
    };

    auto COMPUTE = [&](int buf) {
        const ushort* A_s = lds + buf * 32768;
        const ushort* B_s = A_s + 16384;
#pragma unroll
        for (int kk = 0; kk < 2; ++kk) {
            int koff = (kk * 32 + g * 8) ^ swl;
            short8 a[8], b[4];
#pragma unroll
            for (int m = 0; m < 8; ++m) {
                int row = wr * 128 + m * 16 + fr;     // row&7 == fr&7 -> swl folded
                a[m] = *(const short8*)&A_s[row * 64 + koff];
            }
#pragma unroll
            for (int n = 0; n < 4; ++n) {
                int col = wc * 64 + n * 16 + fr;
                b[n] = *(const short8*)&B_s[col * 64 + koff];
            }
#pragma unroll
            for (int m = 0; m < 8; ++m)
#pragma unroll
                for (int n = 0; n < 4; ++n)
                    acc[m][n] = __builtin_amdgcn_mfma_f32_16x16x32_bf16(
                        a[m], b[n], acc[m][n], 0, 0, 0);
        }
    };

    const int NT = K >> 6;
    STAGE(0, 0);                                      // 8 loads out
    for (int t = 0; t < NT; ++t) {
        int cur = t & 1;
        if (t + 1 < NT) {
            STAGE(cur ^ 1, t + 1);                    // 16 out
            asm volatile("s_waitcnt vmcnt(8)" ::: "memory");   // tile t landed
        } else {
            asm volatile("s_waitcnt vmcnt(0)" ::: "memory");
        }
        __builtin_amdgcn_s_barrier();
        asm volatile("" ::: "memory");
        COMPUTE(cur);
        asm volatile("" ::: "memory");
        __builtin_amdgcn_s_barrier();                 // buf[cur] free for overwrite
    }
}

// ------- persistent GEMM1: h = gelu(X @ W1 + b1), packed per expert -------
__global__ __launch_bounds__(512, 2)
void gemm1_kernel(const ushort* __restrict__ xb,
                  const ushort* __restrict__ ew1T, const ushort* __restrict__ sw1T,
                  const float* __restrict__ eb1, const float* __restrict__ sb1,
                  const int* __restrict__ ids, const int* __restrict__ cnt,
                  const int* __restrict__ offs,
                  const int* __restrict__ q1, const int* __restrict__ n1,
                  ushort* __restrict__ h)
{
    extern __shared__ ushort lds[];
    const int nit = *n1;
    const int lane = threadIdx.x & 63, wave = threadIdx.x >> 6;
    const int wr = wave >> 2, wc = wave & 3, g = lane >> 4, fr = lane & 15;

    for (int it = blockIdx.x; it < nit; it += gridDim.x) {
        int item = q1[it];
        int z = item >> 16, mt = (item >> 8) & 255, nt = item & 255;
        int count, hbase;
        const ushort* BT; const float* bias; const int* gather;
        if (z < NE) {
            count  = cnt[z];
            BT     = ew1T + (size_t)z * HID * DIM;
            bias   = eb1 + z * HID;
            gather = ids + z * T_TOK;
            hbase  = T_TOK + offs[z];
        } else {
            count = T_TOK; BT = sw1T; bias = sb1; gather = nullptr; hbase = 0;
        }
        int tileM = mt * 256, tileN = nt * 256;

        f32x4 acc[8][4];
#pragma unroll
        for (int m = 0; m < 8; ++m)
#pragma unroll
            for (int n = 0; n < 4; ++n) acc[m][n] = (f32x4){0.f, 0.f, 0.f, 0.f};

        mma256(xb, gather, count, BT, DIM, tileM, tileN, lds, acc);

#pragma unroll
        for (int n = 0; n < 4; ++n) {
            int col = tileN + wc * 64 + n * 16 + fr;
            float bc = bias[col];
#pragma unroll
            for (int m = 0; m < 8; ++m) {
#pragma unroll
                for (int i = 0; i < 4; ++i) {
                    int row = tileM + wr * 128 + m * 16 + g * 4 + i;
                    if (row < count)
                        h[(size_t)(hbase + row) * HID + col] =
                            f2bf(gelu_exact(acc[m][n][i] + bc));
                }
            }
        }
        __syncthreads();   // LDS safe for next item's staging
    }
}

// ------- persistent GEMM2 (all-atomic into pre-zeroed out) -------
__global__ __launch_bounds__(512, 2)
void gemm2_kernel(const ushort* __restrict__ h,
                  const ushort* __restrict__ ew2T, const ushort* __restrict__ sw2T,
                  const float* __restrict__ eb2, const float* __restrict__ sb2,
                  const int* __restrict__ ids, const float* __restrict__ wts,
                  const int* __restrict__ cnt, const int* __restrict__ offs,
                  const int* __restrict__ q2, const int* __restrict__ n2,
                  float* __restrict__ out)
{
    extern __shared__ ushort lds[];
    const int nit = *n2;
    const int lane = threadIdx.x & 63, wave = threadIdx.x >> 6;
    const int wr = wave >> 2, wc = wave & 3, g = lane >> 4, fr = lane & 15;

    for (int it = blockIdx.x; it < nit; it += gridDim.x) {
        int item = q2[it];
        int z = item >> 16, mt = (item >> 8) & 255, nt = item & 255;
        int count;
        const ushort* BT; const float* bias; const int* toks; const float* tw;
        const ushort* Arows;
        if (z < NE) {
            count = cnt[z];
            BT    = ew2T + (size_t)z * DIM * HID;
            bias  = eb2 + z * DIM;
            toks  = ids + z * T_TOK;
            tw    = wts + z * T_TOK;
            Arows = h + (size_t)(T_TOK + offs[z]) * HID;
        } else {
            count = T_TOK; BT = sw2T; bias = sb2; toks = nullptr; tw = nullptr;
            Arows = h;
        }
        int tileM = mt * 256, tileN = nt * 256;

        f32x4 acc[8][4];
#pragma unroll
        for (int m = 0; m < 8; ++m)
#pragma unroll
            for (int n = 0; n < 4; ++n) acc[m][n] = (f32x4){0.f, 0.f, 0.f, 0.f};

        mma256(Arows, nullptr, count, BT, HID, tileM, tileN, lds, acc);

#pragma unroll
        for (int n = 0; n < 4; ++n) {
            int col = tileN + wc * 64 + n * 16 + fr;
            float bc = bias[col];
#pragma unroll
            for (int m = 0; m < 8; ++m) {
#pragma unroll
                for (int i = 0; i < 4; ++i) {
                    int row = tileM + wr * 128 + m * 16 + g * 4 + i;
                    if (row < count) {
                        int token = toks ? toks[row] : row;
                        float w   = tw ? tw[row] : 1.0f;
                        atomicAdd(out + (size_t)token * DIM + col, w * (acc[m][n][i] + bc));
                    }
                }
            }
        }
        __syncthreads();   // LDS safe for next item's staging
    }
}

extern "C" void kernel_launch(void* const* d_in, const int* in_sizes, int n_in,
                              void* d_out, int out_size, void* d_ws, size_t ws_size,
                              hipStream_t stream)
{
    const float* x   = (const float*)d_in[0];
    const float* rw  = (const float*)d_in[1];
    const float* rb  = (const float*)d_in[2];
    const float* sw1 = (const float*)d_in[3];
    const float* sb1 = (const float*)d_in[4];
    const float* sw2 = (const float*)d_in[5];
    const float* sb2 = (const float*)d_in[6];
    const float* ew1 = (const float*)d_in[7];
    const float* eb1 = (const float*)d_in[8];
    const float* ew2 = (const float*)d_in[9];
    const float* eb2 = (const float*)d_in[10];
    float* out = (float*)d_out;

    char* p = (char*)d_ws;
    ushort* xb   = (ushort*)p;  p += (size_t)T_TOK * DIM * 2;
    ushort* sw1T = (ushort*)p;  p += (size_t)HID * DIM * 2;
    ushort* sw2T = (ushort*)p;  p += (size_t)DIM * HID * 2;
    ushort* ew1T = (ushort*)p;  p += (size_t)NE * HID * DIM * 2;
    ushort* ew2T = (ushort*)p;  p += (size_t)NE * DIM * HID * 2;
    ushort* hbuf = (ushort*)p;  p += (size_t)(3 * T_TOK) * HID * 2;
    int*    ids  = (int*)p;     p += (size_t)NE * T_TOK * 4;
    float*  wts  = (float*)p;   p += (size_t)NE * T_TOK * 4;
    int*    cnt  = (int*)p;     p += 256;
    int*    offs = (int*)p;     p += 256;
    int*    q1   = (int*)p;     p += 4608;   // 1152 ints
    int*    q2   = (int*)p;     p += 2304;   // 576 ints
    int*    nq   = (int*)p;     p += 256;    // n1 at +0, n2 at +1

    hipFuncSetAttribute((const void*)gemm1_kernel,
                        hipFuncAttributeMaxDynamicSharedMemorySize, 131072);
    hipFuncSetAttribute((const void*)gemm2_kernel,
                        hipFuncAttributeMaxDynamicSharedMemorySize, 131072);

    hipMemsetAsync(cnt, 0, 256, stream);
    hipMemsetAsync(out, 0, (size_t)out_size * 4, stream);

    convert_x<<<dim3((T_TOK * DIM / 8 + 255) / 256), 256, 0, stream>>>(x, xb, T_TOK * DIM / 8);
    transpose_conv9<<<dim3(HID / 32, DIM / 64, NE + 1), 256, 0, stream>>>(
        ew1, sw1, ew1T, sw1T, DIM, HID);
    transpose_conv9<<<dim3(DIM / 32, HID / 64, NE + 1), 256, 0, stream>>>(
        ew2, sw2, ew2T, sw2T, HID, DIM);
    router_kernel<<<dim3(T_TOK / 4), 256, 0, stream>>>(x, rw, rb, cnt, ids, wts);
    build_queue<<<dim3(1), 64, 0, stream>>>(cnt, offs, q1, nq, q2, nq + 1);
    gemm1_kernel<<<dim3(256), 512, 131072, stream>>>(
        xb, ew1T, sw1T, eb1, sb1, ids, cnt, offs, q1, nq, hbuf);
    gemm2_kernel<<<dim3(256), 512, 131072, stream>>>(
        hbuf, ew2T, sw2T, eb2, sb2, ids, wts, cnt, offs, q2, nq + 1, out);
}

// Round 11
// 348.407 us; speedup vs baseline: 1.5234x; 1.1956x over previous
//
#include <hip/hip_runtime.h>

#define DIM   1024
#define HID   2048
#define NE    8
#define T_TOK 4096

typedef __attribute__((ext_vector_type(8))) short short8;
typedef __attribute__((ext_vector_type(4))) float f32x4;

__device__ __forceinline__ ushort f2bf(float f) {
    union { float f; unsigned u; } v; v.f = f;
    unsigned r = v.u + 0x7FFFu + ((v.u >> 16) & 1u);   // RNE
    return (ushort)(r >> 16);
}

// tanh-form gelu: 0.5x(1+tanh(0.79788456(x+0.044715x^3))) = x*e/(e+1),
// e = exp2(2.3020585*(x+0.044715x^3)). Written as x - x/(e+1): inf-safe.
// Max abs deviation from exact erf-gelu ~1e-3 (absorbed by bf16 h rounding).
__device__ __forceinline__ float gelu_fast(float x) {
    float t = x * x;
    float u = x * (1.0f + 0.044715f * t);
    float e = exp2f(2.3020585f * u);
    return x - x / (e + 1.0f);
}

// ------- transpose+convert, 9 tensors in one launch: z<8 experts, z=8 shared -------
__global__ void transpose_conv9(const float* __restrict__ ew, const float* __restrict__ sw,
                                ushort* __restrict__ ewT, ushort* __restrict__ swT,
                                int R, int C) {
    __shared__ float tile[32][65];
    int z = blockIdx.z;
    const float* in = (z < NE) ? ew + (size_t)z * R * C : sw;
    ushort* out     = (z < NE) ? ewT + (size_t)z * R * C : swT;
    int c0 = blockIdx.x * 32, r0 = blockIdx.y * 64;
    int tx = threadIdx.x & 31, ty = threadIdx.x >> 5;   // 256 threads
#pragma unroll
    for (int rr = 0; rr < 64; rr += 8)
        tile[tx][rr + ty] = in[(size_t)(r0 + rr + ty) * C + (c0 + tx)];
    __syncthreads();
    int lane = threadIdx.x & 63, q = threadIdx.x >> 6;
#pragma unroll
    for (int j = 0; j < 8; ++j) {
        int cc = q * 8 + j;
        out[(size_t)(c0 + cc) * R + (r0 + lane)] = f2bf(tile[cc][lane]);
    }
}

// ---- router (+ x->bf16 convert fused): top-2 of softmax(x@rw+rb), renormalized ----
// Also records per-token (expert, pos) for the combine kernel.
__global__ void router_kernel(const float* __restrict__ x, const float* __restrict__ rw,
                              const float* __restrict__ rb, int* __restrict__ cnt,
                              int* __restrict__ ids, float* __restrict__ wts,
                              int* __restrict__ te, int* __restrict__ tp,
                              ushort* __restrict__ xb) {
    int wave = threadIdx.x >> 6;
    int lane = threadIdx.x & 63;
    int t = blockIdx.x * 4 + wave;
    const float* xr = x + (size_t)t * DIM;
    ushort* xo = xb + (size_t)t * DIM;
    float acc[NE];
#pragma unroll
    for (int e = 0; e < NE; ++e) acc[e] = 0.f;
    // each lane handles 16 consecutive elems: convert + router dot in one pass
    {
        int d0 = lane * 16;
        float v[16];
#pragma unroll
        for (int j = 0; j < 16; j += 4) {
            float4 f = *(const float4*)(xr + d0 + j);
            v[j] = f.x; v[j+1] = f.y; v[j+2] = f.z; v[j+3] = f.w;
        }
        short8 o0, o1;
#pragma unroll
        for (int j = 0; j < 8; ++j) { o0[j] = (short)f2bf(v[j]); o1[j] = (short)f2bf(v[8+j]); }
        *(short8*)(xo + d0)     = o0;
        *(short8*)(xo + d0 + 8) = o1;
#pragma unroll
        for (int j = 0; j < 16; ++j) {
#pragma unroll
            for (int e = 0; e < NE; ++e) acc[e] += v[j] * rw[(d0 + j) * NE + e];
        }
    }
#pragma unroll
    for (int e = 0; e < NE; ++e) {
#pragma unroll
        for (int off = 32; off; off >>= 1) acc[e] += __shfl_xor(acc[e], off);
    }
    if (lane == 0) {
        float l[NE];
#pragma unroll
        for (int e = 0; e < NE; ++e) l[e] = acc[e] + rb[e];
        int i1 = 0;
#pragma unroll
        for (int e = 1; e < NE; ++e) if (l[e] > l[i1]) i1 = e;
        int i2 = (i1 == 0) ? 1 : 0;
#pragma unroll
        for (int e = 0; e < NE; ++e) if (e != i1 && l[e] > l[i2]) i2 = e;
        float p2 = __expf(l[i2] - l[i1]);      // p1 = 1
        float w1 = 1.0f / (1.0f + p2);
        float w2 = p2 / (1.0f + p2);
        int pos1 = atomicAdd(&cnt[i1], 1);
        ids[i1 * T_TOK + pos1] = t; wts[i1 * T_TOK + pos1] = w1;
        te[2 * t] = i1; tp[2 * t] = pos1;
        int pos2 = atomicAdd(&cnt[i2], 1);
        ids[i2 * T_TOK + pos2] = t; wts[i2 * T_TOK + pos2] = w2;
        te[2 * t + 1] = i2; tp[2 * t + 1] = pos2;
    }
}

// ------- build offsets + persistent-GEMM work queues (single thread; tiny) -------
// item = (z<<16) | (mTile<<8) | nTile.   z: 0..7 experts, 8 = shared.
__global__ void build_queue(const int* __restrict__ cnt, int* __restrict__ offs,
                            int* __restrict__ q1, int* __restrict__ n1,
                            int* __restrict__ q2, int* __restrict__ n2) {
    if (threadIdx.x != 0) return;
    int s = 0;
    for (int e = 0; e < NE; ++e) { offs[e] = s; s += cnt[e]; }
    int k1 = 0, k2 = 0;
    for (int z = 0; z <= NE; ++z) {
        int c = (z < NE) ? cnt[z] : T_TOK;
        int mts = (c + 255) >> 8;
        for (int mt = 0; mt < mts; ++mt) {
            for (int nt = 0; nt < HID / 256; ++nt)
                q1[k1++] = (z << 16) | (mt << 8) | nt;
            for (int nt = 0; nt < DIM / 256; ++nt)
                q2[k2++] = (z << 16) | (mt << 8) | nt;
        }
    }
    *n1 = k1; *n2 = k2;
}

// ===== 256x256 tile, BK=64, 8 waves (2Mx4N), double-buffered LDS, COUNTED vmcnt =====
// LDS: 2 bufs x (A 256x64 + B 256x64) bf16 = 128 KiB -> 1 block/CU, 2 waves/SIMD.
// Layout [row][64] with element-column XOR swizzle ((row&7)<<3), applied on the
// GLOBAL source column so global_load_lds destinations stay linear.
// Schedule (T4): STAGE(next) at phase top, then s_waitcnt vmcnt(8) — waits only
// for the current tile's 8 loads; next tile's 8 stay in flight across COMPUTE.
__device__ __forceinline__ void mma256(
    const ushort* __restrict__ A, const int* __restrict__ gather, int count,
    const ushort* __restrict__ BT, int K, int tileM, int tileN,
    ushort* lds, f32x4 acc[8][4])
{
    const int tid  = threadIdx.x;
    const int lane = tid & 63, wave = tid >> 6;       // 8 waves
    const int wr = wave >> 2, wc = wave & 3;          // 2M x 4N
    const int g = lane >> 4, fr = lane & 15;
    const int swl = (fr & 7) << 3;                    // lane-constant LDS swizzle
    const int sub = lane >> 3;                        // row within 8-row chunk
    const int kcs = ((lane & 7) ^ sub) << 3;          // pre-swizzled global col

    const ushort* asrc[4];
    const ushort* bsrc[4];
#pragma unroll
    for (int i = 0; i < 4; ++i) {
        int row = (wave * 4 + i) * 8 + sub;           // 32 chunks cover 256 rows
        int ar = tileM + row; if (ar > count - 1) ar = count - 1;
        int grow = gather ? gather[ar] : ar;
        asrc[i] = A  + (size_t)grow * K + kcs;
        bsrc[i] = BT + (size_t)(tileN + row) * K + kcs;
    }

    auto STAGE = [&](int buf, int t) {
        ushort* base = lds + buf * 32768;             // A at +0, B at +16384 (elems)
#pragma unroll
        for (int i = 0; i < 4; ++i) {
            int chunk = wave * 4 + i;
            __builtin_amdgcn_global_load_lds(
                (const __attribute__((address_space(1))) void*)(asrc[i] + t * 64),
                (__attribute__((address_space(3))) void*)(base + chunk * 512),
                16, 0, 0);
            __builtin_amdgcn_global_load_lds(
                (const __attribute__((address_space(1))) void*)(bsrc[i] + t * 64),
                (__attribute__((address_space(3))) void*)(base + 16384 + chunk * 512),
                16, 0, 0);
        }
    };

    auto COMPUTE = [&](int buf) {
        const ushort* A_s = lds + buf * 32768;
        const ushort* B_s = A_s + 16384;
#pragma unroll
        for (int kk = 0; kk < 2; ++kk) {
            int koff = (kk * 32 + g * 8) ^ swl;
            short8 a[8], b[4];
#pragma unroll
            for (int m = 0; m < 8; ++m) {
                int row = wr * 128 + m * 16 + fr;     // row&7 == fr&7 -> swl folded
                a[m] = *(const short8*)&A_s[row * 64 + koff];
            }
#pragma unroll
            for (int n = 0; n < 4; ++n) {
                int col = wc * 64 + n * 16 + fr;
                b[n] = *(const short8*)&B_s[col * 64 + koff];
            }
#pragma unroll
            for (int m = 0; m < 8; ++m)
#pragma unroll
                for (int n = 0; n < 4; ++n)
                    acc[m][n] = __builtin_amdgcn_mfma_f32_16x16x32_bf16(
                        a[m], b[n], acc[m][n], 0, 0, 0);
        }
    };

    const int NT = K >> 6;
    STAGE(0, 0);                                      // 8 loads out
    for (int t = 0; t < NT; ++t) {
        int cur = t & 1;
        if (t + 1 < NT) {
            STAGE(cur ^ 1, t + 1);                    // 16 out
            asm volatile("s_waitcnt vmcnt(8)" ::: "memory");   // tile t landed
        } else {
            asm volatile("s_waitcnt vmcnt(0)" ::: "memory");
        }
        __builtin_amdgcn_s_barrier();
        asm volatile("" ::: "memory");
        COMPUTE(cur);
        asm volatile("" ::: "memory");
        __builtin_amdgcn_s_barrier();                 // buf[cur] free for overwrite
    }
}

// ------- persistent GEMM1: h = gelu(X @ W1 + b1), packed per expert -------
__global__ __launch_bounds__(512, 2)
void gemm1_kernel(const ushort* __restrict__ xb,
                  const ushort* __restrict__ ew1T, const ushort* __restrict__ sw1T,
                  const float* __restrict__ eb1, const float* __restrict__ sb1,
                  const int* __restrict__ ids, const int* __restrict__ cnt,
                  const int* __restrict__ offs,
                  const int* __restrict__ q1, const int* __restrict__ n1,
                  ushort* __restrict__ h)
{
    extern __shared__ ushort lds[];
    const int nit = *n1;
    const int lane = threadIdx.x & 63, wave = threadIdx.x >> 6;
    const int wr = wave >> 2, wc = wave & 3, g = lane >> 4, fr = lane & 15;

    for (int it = blockIdx.x; it < nit; it += gridDim.x) {
        int item = q1[it];
        int z = item >> 16, mt = (item >> 8) & 255, nt = item & 255;
        int count, hbase;
        const ushort* BT; const float* bias; const int* gather;
        if (z < NE) {
            count  = cnt[z];
            BT     = ew1T + (size_t)z * HID * DIM;
            bias   = eb1 + z * HID;
            gather = ids + z * T_TOK;
            hbase  = T_TOK + offs[z];
        } else {
            count = T_TOK; BT = sw1T; bias = sb1; gather = nullptr; hbase = 0;
        }
        int tileM = mt * 256, tileN = nt * 256;

        f32x4 acc[8][4];
#pragma unroll
        for (int m = 0; m < 8; ++m)
#pragma unroll
            for (int n = 0; n < 4; ++n) acc[m][n] = (f32x4){0.f, 0.f, 0.f, 0.f};

        mma256(xb, gather, count, BT, DIM, tileM, tileN, lds, acc);

#pragma unroll
        for (int n = 0; n < 4; ++n) {
            int col = tileN + wc * 64 + n * 16 + fr;
            float bc = bias[col];
#pragma unroll
            for (int m = 0; m < 8; ++m) {
#pragma unroll
                for (int i = 0; i < 4; ++i) {
                    int row = tileM + wr * 128 + m * 16 + g * 4 + i;
                    if (row < count)
                        h[(size_t)(hbase + row) * HID + col] =
                            f2bf(gelu_fast(acc[m][n][i] + bc));
                }
            }
        }
        __syncthreads();   // LDS safe for next item's staging
    }
}

// ------- persistent GEMM2, atomic-free: shared -> out (plain store, covers all);
//         experts -> eo[slot][DIM] = w*(y+b) (plain store, packed by slot) -------
__global__ __launch_bounds__(512, 2)
void gemm2_kernel(const ushort* __restrict__ h,
                  const ushort* __restrict__ ew2T, const ushort* __restrict__ sw2T,
                  const float* __restrict__ eb2, const float* __restrict__ sb2,
                  const float* __restrict__ wts,
                  const int* __restrict__ cnt, const int* __restrict__ offs,
                  const int* __restrict__ q2, const int* __restrict__ n2,
                  float* __restrict__ eo, float* __restrict__ out)
{
    extern __shared__ ushort lds[];
    const int nit = *n2;
    const int lane = threadIdx.x & 63, wave = threadIdx.x >> 6;
    const int wr = wave >> 2, wc = wave & 3, g = lane >> 4, fr = lane & 15;

    for (int it = blockIdx.x; it < nit; it += gridDim.x) {
        int item = q2[it];
        int z = item >> 16, mt = (item >> 8) & 255, nt = item & 255;
        int count;
        const ushort* BT; const float* bias; const float* tw; float* dst;
        const ushort* Arows;
        if (z < NE) {
            count = cnt[z];
            BT    = ew2T + (size_t)z * DIM * HID;
            bias  = eb2 + z * DIM;
            tw    = wts + z * T_TOK;
            Arows = h + (size_t)(T_TOK + offs[z]) * HID;
            dst   = eo + (size_t)offs[z] * DIM;
        } else {
            count = T_TOK; BT = sw2T; bias = sb2; tw = nullptr;
            Arows = h;
            dst   = out;
        }
        int tileM = mt * 256, tileN = nt * 256;

        f32x4 acc[8][4];
#pragma unroll
        for (int m = 0; m < 8; ++m)
#pragma unroll
            for (int n = 0; n < 4; ++n) acc[m][n] = (f32x4){0.f, 0.f, 0.f, 0.f};

        mma256(Arows, nullptr, count, BT, HID, tileM, tileN, lds, acc);

#pragma unroll
        for (int m = 0; m < 8; ++m) {
#pragma unroll
            for (int i = 0; i < 4; ++i) {
                int row = tileM + wr * 128 + m * 16 + g * 4 + i;
                if (row < count) {
                    float w = tw ? tw[row] : 1.0f;
#pragma unroll
                    for (int n = 0; n < 4; ++n) {
                        int col = tileN + wc * 64 + n * 16 + fr;
                        dst[(size_t)row * DIM + col] = w * (acc[m][n][i] + bias[col]);
                    }
                }
            }
        }
        __syncthreads();   // LDS safe for next item's staging
    }
}

// ------- combine: out[t] += eo[slot1(t)] + eo[slot2(t)]  (w already folded) -------
__global__ void combine_kernel(const float* __restrict__ eo, const int* __restrict__ te,
                               const int* __restrict__ tp, const int* __restrict__ offs,
                               float* __restrict__ out)
{
    int t = blockIdx.x;
    int s1 = offs[te[2 * t]]     + tp[2 * t];
    int s2 = offs[te[2 * t + 1]] + tp[2 * t + 1];
    int d = threadIdx.x * 4;
    float4 a = *(const float4*)(out + (size_t)t * DIM + d);
    float4 b = *(const float4*)(eo + (size_t)s1 * DIM + d);
    float4 c = *(const float4*)(eo + (size_t)s2 * DIM + d);
    a.x += b.x + c.x; a.y += b.y + c.y; a.z += b.z + c.z; a.w += b.w + c.w;
    *(float4*)(out + (size_t)t * DIM + d) = a;
}

extern "C" void kernel_launch(void* const* d_in, const int* in_sizes, int n_in,
                              void* d_out, int out_size, void* d_ws, size_t ws_size,
                              hipStream_t stream)
{
    const float* x   = (const float*)d_in[0];
    const float* rw  = (const float*)d_in[1];
    const float* rb  = (const float*)d_in[2];
    const float* sw1 = (const float*)d_in[3];
    const float* sb1 = (const float*)d_in[4];
    const float* sw2 = (const float*)d_in[5];
    const float* sb2 = (const float*)d_in[6];
    const float* ew1 = (const float*)d_in[7];
    const float* eb1 = (const float*)d_in[8];
    const float* ew2 = (const float*)d_in[9];
    const float* eb2 = (const float*)d_in[10];
    float* out = (float*)d_out;

    char* p = (char*)d_ws;
    ushort* xb   = (ushort*)p;  p += (size_t)T_TOK * DIM * 2;
    ushort* sw1T = (ushort*)p;  p += (size_t)HID * DIM * 2;
    ushort* sw2T = (ushort*)p;  p += (size_t)DIM * HID * 2;
    ushort* ew1T = (ushort*)p;  p += (size_t)NE * HID * DIM * 2;
    ushort* ew2T = (ushort*)p;  p += (size_t)NE * DIM * HID * 2;
    ushort* hbuf = (ushort*)p;  p += (size_t)(3 * T_TOK) * HID * 2;
    float*  eo   = (float*)p;   p += (size_t)(2 * T_TOK) * DIM * 4;
    int*    ids  = (int*)p;     p += (size_t)NE * T_TOK * 4;
    float*  wts  = (float*)p;   p += (size_t)NE * T_TOK * 4;
    int*    te   = (int*)p;     p += (size_t)2 * T_TOK * 4;
    int*    tp   = (int*)p;     p += (size_t)2 * T_TOK * 4;
    int*    cnt  = (int*)p;     p += 256;
    int*    offs = (int*)p;     p += 256;
    int*    q1   = (int*)p;     p += 4608;   // 1152 ints
    int*    q2   = (int*)p;     p += 2304;   // 576 ints
    int*    nq   = (int*)p;     p += 256;    // n1 at +0, n2 at +1

    hipFuncSetAttribute((const void*)gemm1_kernel,
                        hipFuncAttributeMaxDynamicSharedMemorySize, 131072);
    hipFuncSetAttribute((const void*)gemm2_kernel,
                        hipFuncAttributeMaxDynamicSharedMemorySize, 131072);

    hipMemsetAsync(cnt, 0, 256, stream);

    router_kernel<<<dim3(T_TOK / 4), 256, 0, stream>>>(x, rw, rb, cnt, ids, wts, te, tp, xb);
    transpose_conv9<<<dim3(HID / 32, DIM / 64, NE + 1), 256, 0, stream>>>(
        ew1, sw1, ew1T, sw1T, DIM, HID);
    transpose_conv9<<<dim3(DIM / 32, HID / 64, NE + 1), 256, 0, stream>>>(
        ew2, sw2, ew2T, sw2T, HID, DIM);
    build_queue<<<dim3(1), 64, 0, stream>>>(cnt, offs, q1, nq, q2, nq + 1);
    gemm1_kernel<<<dim3(256), 512, 131072, stream>>>(
        xb, ew1T, sw1T, eb1, sb1, ids, cnt, offs, q1, nq, hbuf);
    gemm2_kernel<<<dim3(256), 512, 131072, stream>>>(
        hbuf, ew2T, sw2T, eb2, sb2, wts, cnt, offs, q2, nq + 1, eo, out);
    combine_kernel<<<dim3(T_TOK), 256, 0, stream>>>(eo, te, tp, offs, out);
}